// Round 1
// baseline (9.932 us; speedup 1.0000x reference)
//
#include <hip/hip_runtime.h>

// out[c,h,v] = (h==0 ? y[v,c] : fifo[c, h-1, v]) + sum_{i=1..8} fifo[c, i*63+h-1, v]
// y[v,c] = sum_{p<3,u<64} x[p*1024+c, u] * graph[p, u, v]
// Shapes: x (1,3072,1,64) f32; graph (3,64,64) f32; fifo (1,1,1024,512,64) f32
// out (1,1024,8,64) f32.

#define P 3
#define C 1024
#define V 64
#define F 512
#define K 9
#define D 63
#define HOUT 8

__global__ __launch_bounds__(512) void stgcn_kernel(
    const float* __restrict__ x,      // (P*C, V) effectively: idx (p*C+c)*V+u
    const float* __restrict__ graph,  // (P, V, V): idx (p*V+u)*V+v
    const float* __restrict__ fifo,   // (C, F, V): idx (c*F+f)*V+v
    float* __restrict__ out)          // (C, HOUT, V): idx (c*HOUT+h)*V+v
{
    const int c = blockIdx.x;
    const int t = threadIdx.x;      // 0..511
    const int h = t >> 6;           // 0..7
    const int v = t & 63;           // 0..63

    __shared__ float xs[P * V];     // x rows for this c

    if (t < P * V) {
        const int p = t >> 6;
        const int u = t & 63;
        xs[t] = x[(p * C + c) * V + u];
    }
    __syncthreads();

    float acc;
    if (h == 0) {
        // y[v,c] = sum_{p,u} xs[p*64+u] * graph[(p*64+u)*64 + v]
        float s = 0.f;
        #pragma unroll
        for (int pu = 0; pu < P * V; ++pu) {
            s = fmaf(xs[pu], graph[pu * V + v], s);
        }
        acc = s;
    } else {
        acc = fifo[(c * F + (h - 1)) * V + v];
    }

    const float* frow = fifo + (size_t)c * F * V + (size_t)(h - 1) * V + v;
    #pragma unroll
    for (int i = 1; i < K; ++i) {
        acc += frow[(size_t)i * D * V];
    }

    out[(c * HOUT + h) * V + v] = acc;
}

extern "C" void kernel_launch(void* const* d_in, const int* in_sizes, int n_in,
                              void* d_out, int out_size, void* d_ws, size_t ws_size,
                              hipStream_t stream) {
    const float* x     = (const float*)d_in[0];
    const float* graph = (const float*)d_in[1];
    const float* fifo  = (const float*)d_in[2];
    float* out = (float*)d_out;

    stgcn_kernel<<<C, 512, 0, stream>>>(x, graph, fifo, out);
}

// Round 2
// 9.785 us; speedup vs baseline: 1.0151x; 1.0151x over previous
//
#include <hip/hip_runtime.h>

// out[c,h,v] = (h==0 ? y[v,c] : fifo[c, h-1, v]) + sum_{i=1..8} fifo[c, i*63+h-1, v]
// y[v,c] = sum_{p<3,u<64} x[p*1024+c, u] * graph[p, u, v]
// x (3072,64) f32; graph (192,64) f32; fifo (1024,512,64) f32; out (1024,8,64) f32.
//
// Layout: 1 block per c, 128 threads: h = t>>4 (0..7), q = t&15 (v-quad).
// All loads/stores are float4 (16B/lane). The y-GEMM reduction (K=192) is
// split 8 ways across the h-groups (24 pu each, 4 independent FMA chains),
// combined through LDS.

#define P 3
#define C 1024
#define V 64
#define F 512
#define K 9
#define D 63
#define HOUT 8

__global__ __launch_bounds__(128) void stgcn_kernel(
    const float* __restrict__ x,       // (P*C, V)
    const float4* __restrict__ g4,     // (P*V, 16) float4 view of graph
    const float4* __restrict__ fifo4,  // (C*F, 16) float4 view
    float4* __restrict__ out4)         // (C*HOUT, 16) float4 view
{
    const int c = blockIdx.x;
    const int t = threadIdx.x;   // 0..127
    const int h = t >> 4;        // 0..7
    const int q = t & 15;        // 0..15

    __shared__ float  xs[P * V];       // 768 B
    __shared__ float4 part[8][16];     // 2 KB

    // Stage x rows for this c (3 x 256B, coalesced).
    for (int idx = t; idx < P * V; idx += 128) {
        xs[idx] = x[((idx >> 6) * C + c) * V + (idx & 63)];
    }
    __syncthreads();

    // Partial y: group h covers pu in [h*24, h*24+24).
    float ax = 0.f, ay = 0.f, az = 0.f, aw = 0.f;
    const int pu0 = h * 24;
    #pragma unroll
    for (int i = 0; i < 24; ++i) {
        const int pu = pu0 + i;
        const float  xv = xs[pu];
        const float4 gg = g4[pu * 16 + q];   // L2-resident, coalesced
        ax = fmaf(xv, gg.x, ax);
        ay = fmaf(xv, gg.y, ay);
        az = fmaf(xv, gg.z, az);
        aw = fmaf(xv, gg.w, aw);
    }
    part[h][q] = make_float4(ax, ay, az, aw);

    // FIFO taps: base row is (h-1); taps at (h-1) + i*63, i=1..8.
    const long base = (long)c * (F * 16) + (long)(h - 1) * 16 + q;  // float4 units
    float rx, ry, rz, rw;
    float4 f0;
    if (h > 0) {
        f0 = fifo4[base];
    }

    float4 tap[K - 1];
    #pragma unroll
    for (int i = 1; i < K; ++i) {
        tap[i - 1] = fifo4[base + (long)i * (D * 16)];
    }

    __syncthreads();

    if (h == 0) {
        float4 s = part[0][q];
        rx = s.x; ry = s.y; rz = s.z; rw = s.w;
        #pragma unroll
        for (int g = 1; g < 8; ++g) {
            float4 pgq = part[g][q];
            rx += pgq.x; ry += pgq.y; rz += pgq.z; rw += pgq.w;
        }
    } else {
        rx = f0.x; ry = f0.y; rz = f0.z; rw = f0.w;
    }

    #pragma unroll
    for (int i = 0; i < K - 1; ++i) {
        rx += tap[i].x; ry += tap[i].y; rz += tap[i].z; rw += tap[i].w;
    }

    out4[(c * HOUT + h) * 16 + q] = make_float4(rx, ry, rz, rw);
}

extern "C" void kernel_launch(void* const* d_in, const int* in_sizes, int n_in,
                              void* d_out, int out_size, void* d_ws, size_t ws_size,
                              hipStream_t stream) {
    const float*  x     = (const float*)d_in[0];
    const float4* graph = (const float4*)d_in[1];
    const float4* fifo  = (const float4*)d_in[2];
    float4* out = (float4*)d_out;

    stgcn_kernel<<<C, 128, 0, stream>>>(x, graph, fifo, out);
}